// Round 2
// baseline (4116.282 us; speedup 1.0000x reference)
//
#include <hip/hip_runtime.h>

#define BATCH    128
#define NPTS     32768
#define KOUT     1024
#define NTHREADS 1024
#define PPT      (NPTS / NTHREADS)   // 32 points per thread

// Dynamic LDS: mindist[NPTS] = 128 KiB
extern __shared__ float s_md[];

__global__ __launch_bounds__(NTHREADS)
void fps_kernel(const float* __restrict__ x, float* __restrict__ out) {
    __shared__ float s_redv[16];
    __shared__ int   s_redi[16];
    __shared__ float s_pt[3];
    __shared__ int   s_bi;

    const int b   = blockIdx.x;
    const int tid = threadIdx.x;
    const float* __restrict__ xb = x + (size_t)b * 3 * NPTS;
    float* __restrict__ ob = out + (size_t)b * 3 * KOUT;

    // Load this thread's 32 points (strided: n = tid + i*1024, coalesced).
    float xs[PPT], ys[PPT], zs[PPT];
#pragma unroll
    for (int i = 0; i < PPT; ++i) {
        const int n = tid + i * NTHREADS;
        xs[i] = xb[n];
        ys[i] = xb[NPTS + n];
        zs[i] = xb[2 * NPTS + n];
        s_md[n] = 1e10f;
    }

    // First selected point is index 0 (all threads broadcast-load its coords).
    float px = xb[0], py = xb[NPTS], pz = xb[2 * NPTS];
    if (tid == 0) {
        ob[0] = px; ob[KOUT] = py; ob[2 * KOUT] = pz;
    }
    __syncthreads();

    const int lane = tid & 63;
    const int wave = tid >> 6;

    for (int j = 1; j < KOUT; ++j) {
        float best = -1.0f;
        int   bi   = 0x7fffffff;

        // Distance update + running (first-occurrence) argmax.
        // Match XLA's contracted reduce: acc=0; acc=fma(dx,dx,acc);
        // acc=fma(dy,dy,acc); acc=fma(dz,dz,acc). fma(dx,dx,0)==rn(dx*dx).
#pragma unroll
        for (int i = 0; i < PPT; ++i) {
            const int n = tid + i * NTHREADS;
            const float dx = __fsub_rn(xs[i], px);
            const float dy = __fsub_rn(ys[i], py);
            const float dz = __fsub_rn(zs[i], pz);
            const float d  = __fmaf_rn(dz, dz,
                              __fmaf_rn(dy, dy,
                                __fmul_rn(dx, dx)));
            const float m  = fminf(s_md[n], d);
            s_md[n] = m;
            // within a thread indices increase with i, so strict > keeps the
            // earliest (lowest-index) occurrence of the max
            if (m > best) { best = m; bi = n; }
        }

        // Wave-level butterfly argmax (tie-break: smaller index wins).
#pragma unroll
        for (int s = 1; s < 64; s <<= 1) {
            const float ov = __shfl_xor(best, s, 64);
            const int   oi = __shfl_xor(bi,   s, 64);
            if (ov > best || (ov == best && oi < bi)) { best = ov; bi = oi; }
        }
        if (lane == 0) { s_redv[wave] = best; s_redi[wave] = bi; }
        __syncthreads();

        // Cross-wave reduce (16 partials) in wave 0.
        if (wave == 0) {
            float v  = (lane < 16) ? s_redv[lane] : -1.0f;
            int   vi = (lane < 16) ? s_redi[lane] : 0x7fffffff;
#pragma unroll
            for (int s = 1; s < 16; s <<= 1) {
                const float ov = __shfl_xor(v,  s, 64);
                const int   oi = __shfl_xor(vi, s, 64);
                if (ov > v || (ov == v && oi < vi)) { v = ov; vi = oi; }
            }
            if (lane == 0) s_bi = vi;
        }
        __syncthreads();

        const int gbi = s_bi;
        // Winner thread extracts the selected point's coords from its
        // registers (static unrolled select, rule #20: no runtime indexing)
        // and publishes them + writes the output.
        if (tid == (gbi & (NTHREADS - 1))) {
            const int ii = gbi >> 10;
            float sx = 0.f, sy = 0.f, sz = 0.f;
#pragma unroll
            for (int q = 0; q < PPT; ++q) {
                if (q == ii) { sx = xs[q]; sy = ys[q]; sz = zs[q]; }
            }
            s_pt[0] = sx; s_pt[1] = sy; s_pt[2] = sz;
            ob[j] = sx; ob[KOUT + j] = sy; ob[2 * KOUT + j] = sz;
        }
        __syncthreads();
        px = s_pt[0]; py = s_pt[1]; pz = s_pt[2];
    }
}

extern "C" void kernel_launch(void* const* d_in, const int* in_sizes, int n_in,
                              void* d_out, int out_size, void* d_ws, size_t ws_size,
                              hipStream_t stream) {
    const float* x = (const float*)d_in[0];
    float* out = (float*)d_out;

    const size_t dyn_lds = (size_t)NPTS * sizeof(float);  // 128 KiB
    hipFuncSetAttribute((const void*)fps_kernel,
                        hipFuncAttributeMaxDynamicSharedMemorySize,
                        (int)dyn_lds);
    fps_kernel<<<BATCH, NTHREADS, dyn_lds, stream>>>(x, out);
}

// Round 3
// 3606.660 us; speedup vs baseline: 1.1413x; 1.1413x over previous
//
#include <hip/hip_runtime.h>

#define BATCH    128
#define NPTS     32768
#define KOUT     1024
#define NTHREADS 1024
#define PPT      (NPTS / NTHREADS)   // 32 points per thread

// Dynamic LDS: mindist[NPTS] = 128 KiB
extern __shared__ float s_md[];

// 4 waves/EU * 4 EU = 16 waves/CU = exactly one 1024-thread block per CU
// (128 KiB LDS already limits us to 1 block/CU). This raises the VGPR cap
// from 64 to 128 so the 96 coord registers stay resident instead of
// spilling (round-2 kernel reported VGPR_Count=64 -> coords were spilled,
// VALUBusy was 35%).
__global__ __launch_bounds__(NTHREADS, 4)
void fps_kernel(const float* __restrict__ x, float* __restrict__ out) {
    __shared__ float s_redv[16];
    __shared__ int   s_redi[16];
    __shared__ float s_pt[3];

    const int b   = blockIdx.x;
    const int tid = threadIdx.x;
    const float* __restrict__ xb = x + (size_t)b * 3 * NPTS;
    float* __restrict__ ob = out + (size_t)b * 3 * KOUT;

    // Load this thread's 32 points (strided: n = tid + i*1024, coalesced).
    float xs[PPT], ys[PPT], zs[PPT];
#pragma unroll
    for (int i = 0; i < PPT; ++i) {
        const int n = tid + i * NTHREADS;
        xs[i] = xb[n];
        ys[i] = xb[NPTS + n];
        zs[i] = xb[2 * NPTS + n];
        s_md[n] = 1e10f;
    }

    // First selected point is index 0.
    float px = xb[0], py = xb[NPTS], pz = xb[2 * NPTS];
    if (tid == 0) {
        ob[0] = px; ob[KOUT] = py; ob[2 * KOUT] = pz;
    }
    __syncthreads();

    const int lane = tid & 63;
    const int wave = tid >> 6;

    for (int j = 1; j < KOUT; ++j) {
        float best = -1.0f;
        int   bi   = 0x7fffffff;

        // Distance update + running (first-occurrence) argmax.
        // Bit-exact vs reference (verified round 2, absmax 0):
        //   d = fma(dz,dz, fma(dy,dy, rn(dx*dx)))
#pragma unroll
        for (int i = 0; i < PPT; ++i) {
            const int n = tid + i * NTHREADS;
            const float dx = __fsub_rn(xs[i], px);
            const float dy = __fsub_rn(ys[i], py);
            const float dz = __fsub_rn(zs[i], pz);
            const float d  = __fmaf_rn(dz, dz,
                              __fmaf_rn(dy, dy,
                                __fmul_rn(dx, dx)));
            const float m  = fminf(s_md[n], d);
            s_md[n] = m;
            // indices increase with i, so strict > keeps the earliest
            // (lowest-index) occurrence of the max
            if (m > best) { best = m; bi = n; }
        }

        // Wave-level butterfly argmax (tie-break: smaller index wins).
#pragma unroll
        for (int s = 1; s < 64; s <<= 1) {
            const float ov = __shfl_xor(best, s, 64);
            const int   oi = __shfl_xor(bi,   s, 64);
            if (ov > best || (ov == best && oi < bi)) { best = ov; bi = oi; }
        }
        if (lane == 0) { s_redv[wave] = best; s_redi[wave] = bi; }
        __syncthreads();

        // Cross-wave reduce (16 partials) in wave 0; lane 0 then fetches the
        // winner's coords straight from global (L2-resident) — no winner-
        // thread register extract, no third barrier.
        if (wave == 0) {
            float v  = (lane < 16) ? s_redv[lane] : -1.0f;
            int   vi = (lane < 16) ? s_redi[lane] : 0x7fffffff;
#pragma unroll
            for (int s = 1; s < 16; s <<= 1) {
                const float ov = __shfl_xor(v,  s, 64);
                const int   oi = __shfl_xor(vi, s, 64);
                if (ov > v || (ov == v && oi < vi)) { v = ov; vi = oi; }
            }
            if (lane == 0) {
                const float sx = xb[vi];
                const float sy = xb[NPTS + vi];
                const float sz = xb[2 * NPTS + vi];
                s_pt[0] = sx; s_pt[1] = sy; s_pt[2] = sz;
                ob[j] = sx; ob[KOUT + j] = sy; ob[2 * KOUT + j] = sz;
            }
        }
        __syncthreads();
        px = s_pt[0]; py = s_pt[1]; pz = s_pt[2];
    }
}

extern "C" void kernel_launch(void* const* d_in, const int* in_sizes, int n_in,
                              void* d_out, int out_size, void* d_ws, size_t ws_size,
                              hipStream_t stream) {
    const float* x = (const float*)d_in[0];
    float* out = (float*)d_out;

    const size_t dyn_lds = (size_t)NPTS * sizeof(float);  // 128 KiB
    hipFuncSetAttribute((const void*)fps_kernel,
                        hipFuncAttributeMaxDynamicSharedMemorySize,
                        (int)dyn_lds);
    fps_kernel<<<BATCH, NTHREADS, dyn_lds, stream>>>(x, out);
}

// Round 4
// 3603.622 us; speedup vs baseline: 1.1423x; 1.0008x over previous
//
#include <hip/hip_runtime.h>

#define BATCH    128
#define NPTS     32768
#define KOUT     1024
#define NTHREADS 1024
#define PPT      (NPTS / NTHREADS)   // 32 points per thread

// Dynamic LDS: mindist[NPTS] = 128 KiB
extern __shared__ float s_md[];

// 1024-thread block = 16 waves, all co-resident on one CU = 4 waves/EU.
// amdgpu_waves_per_eu(4,4) pins the occupancy TARGET so the register
// allocator budgets 128 VGPRs instead of throttling to 64 (which made it
// rematerialize the 96 coord registers from global every iteration —
// round-3 showed VGPR_Count=64, VALUBusy 39%, ~13.6 TB/s of L3 re-reads).
__global__ __launch_bounds__(NTHREADS)
__attribute__((amdgpu_waves_per_eu(4, 4)))
void fps_kernel(const float* __restrict__ x, float* __restrict__ out) {
    __shared__ float s_redv[16];
    __shared__ int   s_redi[16];
    __shared__ float s_pt[3];

    const int b   = blockIdx.x;
    const int tid = threadIdx.x;
    const float* __restrict__ xb = x + (size_t)b * 3 * NPTS;
    float* __restrict__ ob = out + (size_t)b * 3 * KOUT;

    // Load this thread's 32 points (strided: n = tid + i*1024, coalesced).
    float xs[PPT], ys[PPT], zs[PPT];
#pragma unroll
    for (int i = 0; i < PPT; ++i) {
        const int n = tid + i * NTHREADS;
        xs[i] = xb[n];
        ys[i] = xb[NPTS + n];
        zs[i] = xb[2 * NPTS + n];
        s_md[n] = 1e10f;
    }

    // First selected point is index 0.
    float px = xb[0], py = xb[NPTS], pz = xb[2 * NPTS];
    if (tid == 0) {
        ob[0] = px; ob[KOUT] = py; ob[2 * KOUT] = pz;
    }
    __syncthreads();

    const int lane = tid & 63;
    const int wave = tid >> 6;

    for (int j = 1; j < KOUT; ++j) {
        float best = -1.0f;
        int   bi   = 0x7fffffff;

        // Distance update + running (first-occurrence) argmax.
        // Bit-exact vs reference (verified round 2, absmax 0):
        //   d = fma(dz,dz, fma(dy,dy, rn(dx*dx)))
#pragma unroll
        for (int i = 0; i < PPT; ++i) {
            const int n = tid + i * NTHREADS;
            const float dx = __fsub_rn(xs[i], px);
            const float dy = __fsub_rn(ys[i], py);
            const float dz = __fsub_rn(zs[i], pz);
            const float d  = __fmaf_rn(dz, dz,
                              __fmaf_rn(dy, dy,
                                __fmul_rn(dx, dx)));
            const float m  = fminf(s_md[n], d);
            s_md[n] = m;
            // indices increase with i, so strict > keeps the earliest
            // (lowest-index) occurrence of the max
            if (m > best) { best = m; bi = n; }
        }

        // Wave-level butterfly argmax (tie-break: smaller index wins).
#pragma unroll
        for (int s = 1; s < 64; s <<= 1) {
            const float ov = __shfl_xor(best, s, 64);
            const int   oi = __shfl_xor(bi,   s, 64);
            if (ov > best || (ov == best && oi < bi)) { best = ov; bi = oi; }
        }
        if (lane == 0) { s_redv[wave] = best; s_redi[wave] = bi; }
        __syncthreads();

        // Cross-wave reduce (16 partials) in wave 0; lane 0 then fetches the
        // winner's coords straight from global (L2-resident) and publishes.
        if (wave == 0) {
            float v  = (lane < 16) ? s_redv[lane] : -1.0f;
            int   vi = (lane < 16) ? s_redi[lane] : 0x7fffffff;
#pragma unroll
            for (int s = 1; s < 16; s <<= 1) {
                const float ov = __shfl_xor(v,  s, 64);
                const int   oi = __shfl_xor(vi, s, 64);
                if (ov > v || (ov == v && oi < vi)) { v = ov; vi = oi; }
            }
            if (lane == 0) {
                const float sx = xb[vi];
                const float sy = xb[NPTS + vi];
                const float sz = xb[2 * NPTS + vi];
                s_pt[0] = sx; s_pt[1] = sy; s_pt[2] = sz;
                ob[j] = sx; ob[KOUT + j] = sy; ob[2 * KOUT + j] = sz;
            }
        }
        __syncthreads();
        px = s_pt[0]; py = s_pt[1]; pz = s_pt[2];
    }
}

extern "C" void kernel_launch(void* const* d_in, const int* in_sizes, int n_in,
                              void* d_out, int out_size, void* d_ws, size_t ws_size,
                              hipStream_t stream) {
    const float* x = (const float*)d_in[0];
    float* out = (float*)d_out;

    const size_t dyn_lds = (size_t)NPTS * sizeof(float);  // 128 KiB
    hipFuncSetAttribute((const void*)fps_kernel,
                        hipFuncAttributeMaxDynamicSharedMemorySize,
                        (int)dyn_lds);
    fps_kernel<<<BATCH, NTHREADS, dyn_lds, stream>>>(x, out);
}